// Round 17
// baseline (1586.102 us; speedup 1.0000x reference)
//
#include <hip/hip_runtime.h>
#include <hip/hip_bf16.h>
#include <math.h>

typedef __hip_bfloat16 bf16;
typedef __attribute__((ext_vector_type(4))) float f32x4;
typedef __attribute__((ext_vector_type(8))) short bf16x8s;

#define T_SEQ 4096
#define MFMA16(a, b, c) __builtin_amdgcn_mfma_f32_16x16x32_bf16(a, b, c, 0, 0, 0)
#define AS1 __attribute__((address_space(1)))
#define AS3 __attribute__((address_space(3)))

static __device__ __forceinline__ float bf2f(short u) {
    return __uint_as_float(((unsigned int)(unsigned short)u) << 16);
}
static __device__ __forceinline__ short f2bf(float f) {
    bf16 h = __float2bfloat16(f);
    union { bf16 b; short s; } c; c.b = h; return c.s;
}
static __device__ __forceinline__ int swz_f(int r) { return (r & 7) ^ (r >> 3); }

// ---------------- f32 -> bf16 conversion (vectorized) ----------------
__global__ void cvt_f32_bf16(const float* __restrict__ src, bf16* __restrict__ dst, int n8) {
    int i = blockIdx.x * 256 + threadIdx.x;
    if (i >= n8) return;
    f32x4 a = ((const f32x4*)src)[(size_t)i * 2];
    f32x4 b = ((const f32x4*)src)[(size_t)i * 2 + 1];
    union { bf16 h[8]; uint4 u; } p;
    p.h[0] = __float2bfloat16(a.x); p.h[1] = __float2bfloat16(a.y);
    p.h[2] = __float2bfloat16(a.z); p.h[3] = __float2bfloat16(a.w);
    p.h[4] = __float2bfloat16(b.x); p.h[5] = __float2bfloat16(b.y);
    p.h[6] = __float2bfloat16(b.z); p.h[7] = __float2bfloat16(b.w);
    ((uint4*)dst)[i] = p.u;
}

// ============ 256x256 tile, BK=32, 8-wave, 64 KiB LDS (2 blocks/CU) ============
// Occupancy experiment: halve LDS (2 slots/side, BK=32) so 2 blocks co-reside per
// CU -> cross-block TLP covers barrier/drain stalls (m114 mechanism).
// Per tile t (slot s=t&1): phA: ds_read bfr[4]+afr[0-3] | stage FULL tile t+1
// (A+B, 4 GLL) into slot s^1 | barrier,16 MFMA,barrier ; phB: ds_read afr[4-7] |
// vmcnt(0) (drains t+1; ~1.5 phases of cover; other block runs during drain) |
// barrier,16 MFMA,barrier. WAR safe: slot s^1's reads completed before tile t-1's
// closing barrier; visibility: vmcnt(0) + barrier before phA(t+1) reads.
// MODE 0 (N-grid 12): bx<4 Q block (f32 softmax epilogue); bx>=4 KV block:
// TWO-PASS epilogue (64 KiB = 4 units/pass): pass p: wr==p waves scatter
// exp(K)/V + reg-ksum; waves 0-3 compute ctx=K^T V for units p*4+wid.
// MODE 1: plain f32 out.
template<int MODE>
__global__ __launch_bounds__(512, 4)
void gemm256(const bf16* __restrict__ A, const bf16* __restrict__ Bm,
             int K, int N,
             bf16* __restrict__ out0, bf16* __restrict__ ctxb, float* __restrict__ ksum,
             float* __restrict__ outf)
{
    __shared__ __align__(16) short SMEM[32768];   // 64 KiB: A slots s*8192; B: 16384+s*8192
    const int tid  = threadIdx.x;
    const int l    = tid & 63;
    const int wid  = tid >> 6;
    const int wr   = wid >> 2;           // 0..1
    const int wc   = wid & 3;            // 0..3

    // XCD-chunked bijective swizzle (grid % 8 == 0)
    const int nwg  = gridDim.x * gridDim.y;
    const int flat = blockIdx.y * gridDim.x + blockIdx.x;
    const int swzb = (flat & 7) * (nwg >> 3) + (flat >> 3);
    const int bx   = swzb % gridDim.x;
    const int by   = swzb / gridDim.x;
    const int brow = by * 256;
    const int bcol = bx * 256;
    const int nkt  = K >> 5;             // BK=32; must be even

    const bool isKV = (MODE == 0) && (bx >= 4);
    const int  jkv  = bx - 4;
    const int  b0row = isKV ? (1024 + jkv * 128) : bcol;
    const int  b1row = isKV ? (2048 + jkv * 128) : bcol + 128;

    const int chnk = (l >> 4) ^ (((l & 15) >> 1) & 3);
    const short* baseA = &SMEM[(wr * 128 + (l & 15)) * 32 + chnk * 8];
    const short* baseB = &SMEM[16384 + (wc * 64 + (l & 15)) * 32 + chnk * 8];
#define RDA(SLOT, M_) (*(const bf16x8s*)(baseA + (SLOT) * 8192 + (M_) * 512))
#define RDB(SLOT, N_) (*(const bf16x8s*)(baseB + (SLOT) * 8192 + (N_) * 512))

    const int srow = tid >> 2;
    const int scs  = (tid & 3) ^ ((srow >> 1) & 3);
    const bf16* gA0 = A  + (size_t)(brow + srow) * K + scs * 8;
    const bf16* gA1 = A  + (size_t)(brow + 128 + srow) * K + scs * 8;
    const bf16* gB0 = Bm + (size_t)(b0row + srow) * K + scs * 8;
    const bf16* gB1 = Bm + (size_t)(b1row + srow) * K + scs * 8;
#define GLLT(PTR, SLOT, ISB, EXTRA)                                               \
    __builtin_amdgcn_global_load_lds((const AS1 void*)(PTR),                      \
        (AS3 void*)&SMEM[(ISB) * 16384 + (SLOT) * 8192 + (EXTRA) + tid * 8], 16, 0, 0)

    f32x4 acc[8][4];
#pragma unroll
    for (int m = 0; m < 8; ++m)
#pragma unroll
        for (int n = 0; n < 4; ++n) acc[m][n] = (f32x4){0.f, 0.f, 0.f, 0.f};

    // ---- prologue: stage tile 0 into slot 0 ----
    GLLT(gA0, 0, 0, 0);  GLLT(gA1, 0, 0, 4096);
    GLLT(gB0, 0, 1, 0);  GLLT(gB1, 0, 1, 4096);
    asm volatile("s_waitcnt vmcnt(0)" ::: "memory");
    __builtin_amdgcn_s_barrier();

    const bf16 *pA0 = gA0 + 32, *pA1 = gA1 + 32, *pB0 = gB0 + 32, *pB1 = gB1 + 32;

#define MFMA_BLOCK(ACCOFF)                                                        \
    __builtin_amdgcn_s_barrier();                                                 \
    __builtin_amdgcn_s_setprio(1);                                                \
    _Pragma("unroll")                                                             \
    for (int m = 0; m < 4; ++m)                                                   \
        _Pragma("unroll")                                                         \
        for (int n = 0; n < 4; ++n)                                               \
            acc[m + (ACCOFF)][n] = MFMA16(afr[m], bfr[n], acc[m + (ACCOFF)][n]);  \
    __builtin_amdgcn_s_setprio(0);                                                \
    __builtin_amdgcn_s_barrier();

#define TILE(S, NS, TT)                                                           \
    {                                                                             \
        const bool pf = ((TT) + 1 < nkt);                                         \
        bf16x8s afr[4], bfr[4];                                                   \
        _Pragma("unroll") for (int n = 0; n < 4; ++n) bfr[n] = RDB(S, n);         \
        _Pragma("unroll") for (int m = 0; m < 4; ++m) afr[m] = RDA(S, m);         \
        if (pf) { GLLT(pA0, NS, 0, 0); GLLT(pA1, NS, 0, 4096);                    \
                  GLLT(pB0, NS, 1, 0); GLLT(pB1, NS, 1, 4096); }                  \
        MFMA_BLOCK(0)                                                             \
        _Pragma("unroll") for (int m = 0; m < 4; ++m) afr[m] = RDA(S, m + 4);     \
        asm volatile("s_waitcnt vmcnt(0)" ::: "memory");                          \
        MFMA_BLOCK(4)                                                             \
        pA0 += 32; pA1 += 32; pB0 += 32; pB1 += 32;                               \
    }

    for (int t = 0; t < nkt; t += 2) {
        TILE(0, 1, t)
        TILE(1, 0, t + 1)
    }

    if (MODE == 1) {
#pragma unroll
        for (int m = 0; m < 8; ++m) {
            int row = brow + wr * 128 + m * 16 + ((l >> 4) << 2);
#pragma unroll
            for (int n = 0; n < 4; ++n) {
                int col = bcol + wc * 64 + n * 16 + (l & 15);
#pragma unroll
                for (int r = 0; r < 4; ++r)
                    outf[(size_t)(row + r) * N + col] = acc[m][n][r];
            }
        }
    } else if (!isKV) {
        // ---- Q epilogue: f32 row-softmax over the 64-wide head (this wave's wc) ----
#pragma unroll
        for (int m = 0; m < 8; ++m) {
            int row = brow + wr * 128 + m * 16 + ((l >> 4) << 2);
#pragma unroll
            for (int r = 0; r < 4; ++r) {
                float v0 = acc[m][0][r], v1 = acc[m][1][r], v2 = acc[m][2][r], v3 = acc[m][3][r];
                float mx = fmaxf(fmaxf(v0, v1), fmaxf(v2, v3));
#pragma unroll
                for (int off = 8; off; off >>= 1) mx = fmaxf(mx, __shfl_xor(mx, off));
                float e0 = __expf(v0 - mx), e1 = __expf(v1 - mx);
                float e2 = __expf(v2 - mx), e3 = __expf(v3 - mx);
                float sm = e0 + e1 + e2 + e3;
#pragma unroll
                for (int off = 8; off; off >>= 1) sm += __shfl_xor(sm, off);
                float inv = 0.125f / sm;
                size_t rr = (size_t)(row + r);
                int cb = bcol + wc * 64 + (l & 15);
                out0[rr * 1024 + cb]      = __float2bfloat16(e0 * inv);
                out0[rr * 1024 + cb + 16] = __float2bfloat16(e1 * inv);
                out0[rr * 1024 + cb + 32] = __float2bfloat16(e2 * inv);
                out0[rr * 1024 + cb + 48] = __float2bfloat16(e3 * inv);
            }
        }
    } else {
        // ---- KV epilogue, TWO-PASS (64 KiB): pass p handles units p*4..p*4+3 ----
        const int hl = wc & 1;                       // head_local (K: wc 0,1; V: wc 2,3)
        short* side = (short*)SMEM + ((wc >= 2) ? 16384 : 0);
#pragma unroll
        for (int p = 0; p < 2; ++p) {
            if (p) __syncthreads();                  // protect pass-0 LDS from overwrite
            if (wr == p) {
                float ks[2][4];
#pragma unroll
                for (int u = 0; u < 2; ++u)
#pragma unroll
                    for (int n = 0; n < 4; ++n) ks[u][n] = 0.f;
#pragma unroll
                for (int m = 0; m < 8; ++m) {
                    const int ubase = (m >> 2) * 8192 + hl * 4096;   // local unit*4096
                    const int s0 = (m & 3) * 16 + ((l >> 4) << 2);
                    const int sc = s0 >> 3, slo = s0 & 7;
#pragma unroll
                    for (int n = 0; n < 4; ++n) {
                        int d = n * 16 + (l & 15);
                        union { short h4[4]; uint2 u2; } pk;
                        if (wc < 2) {
                            float e0 = __expf(acc[m][n][0]), e1 = __expf(acc[m][n][1]);
                            float e2 = __expf(acc[m][n][2]), e3 = __expf(acc[m][n][3]);
                            ks[m >> 2][n] += (e0 + e1) + (e2 + e3);
                            pk.h4[0] = f2bf(e0); pk.h4[1] = f2bf(e1);
                            pk.h4[2] = f2bf(e2); pk.h4[3] = f2bf(e3);
                        } else {
                            pk.h4[0] = f2bf(acc[m][n][0]); pk.h4[1] = f2bf(acc[m][n][1]);
                            pk.h4[2] = f2bf(acc[m][n][2]); pk.h4[3] = f2bf(acc[m][n][3]);
                        }
                        *(uint2*)&side[ubase + d * 64 + ((sc ^ swz_f(d)) << 3) + slo] = pk.u2;
                    }
                }
                if (wc < 2) {   // finish ksum: lanes l, l^16, l^32 share d
#pragma unroll
                    for (int u = 0; u < 2; ++u)
#pragma unroll
                        for (int n = 0; n < 4; ++n) {
                            float s = ks[u][n];
                            s += __shfl_xor(s, 16);
                            s += __shfl_xor(s, 32);
                            if ((l >> 4) == 0) {
                                int unit = p * 4 + u * 2 + hl;
                                int gr0 = brow + (unit >> 1) * 64;
                                size_t bidu = (size_t)(((gr0 >> 12) * 16) + jkv * 2 + (unit & 1)) * 64
                                              + ((gr0 & 4095) >> 6);
                                ksum[bidu * 64 + n * 16 + (l & 15)] = s;
                            }
                        }
                }
            }
            __syncthreads();
            if (wid < 4) {
                const int gu = p * 4 + wid;
                const int gr0 = brow + (gu >> 1) * 64;
                const size_t bid = (size_t)(((gr0 >> 12) * 16) + jkv * 2 + (gu & 1)) * 64
                                   + ((gr0 & 4095) >> 6);
                const short* k_u = (const short*)SMEM + wid * 4096;
                const short* v_u = (const short*)SMEM + 16384 + wid * 4096;

                f32x4 a16[4][4];
#pragma unroll
                for (int m = 0; m < 4; ++m)
#pragma unroll
                    for (int n = 0; n < 4; ++n) a16[m][n] = (f32x4){0.f, 0.f, 0.f, 0.f};
#pragma unroll
                for (int kk = 0; kk < 2; ++kk) {
                    const int cc = kk * 4 + (l >> 4);
                    bf16x8s af[4], bf[4];
#pragma unroll
                    for (int m = 0; m < 4; ++m) {
                        int rA = m * 16 + (l & 15);
                        af[m] = *(const bf16x8s*)&k_u[rA * 64 + ((cc ^ swz_f(rA)) << 3)];
                        bf[m] = *(const bf16x8s*)&v_u[rA * 64 + ((cc ^ swz_f(rA)) << 3)];
                    }
#pragma unroll
                    for (int m = 0; m < 4; ++m)
#pragma unroll
                        for (int n = 0; n < 4; ++n)
                            a16[m][n] = MFMA16(af[m], bf[n], a16[m][n]);
                }
                bf16* rec = ctxb + bid * 4096;
#pragma unroll
                for (int m = 0; m < 4; ++m) {
                    int d0 = m * 16 + ((l >> 4) << 2);
#pragma unroll
                    for (int n = 0; n < 4; ++n) {
                        int e = n * 16 + (l & 15);
                        ushort4 o;
                        o.x = (ushort)f2bf(a16[m][n][0]); o.y = (ushort)f2bf(a16[m][n][1]);
                        o.z = (ushort)f2bf(a16[m][n][2]); o.w = (ushort)f2bf(a16[m][n][3]);
                        *(ushort4*)&rec[e * 64 + d0] = o;
                    }
                }
            }
        }
    }
#undef RDA
#undef RDB
#undef GLLT
#undef MFMA_BLOCK
#undef TILE
}

// ---------------- exclusive cumsum over buckets ----------------
// grid (5, 64): x<4 -> ctx chains (bf16 in, f32 accum, bf16 out); x==4 -> ksum (f32)
__global__ void cumsum_excl(const bf16* __restrict__ ctxb, const float* __restrict__ ksum,
                            bf16* __restrict__ ctp, float* __restrict__ ksump)
{
    const int bh = blockIdx.y;
    if (blockIdx.x == 4) {
        int d = threadIdx.x;
        if (d >= 64) return;
        float run = 0.f;
        for (int j = 0; j < 64; ++j) {
            size_t idx = (size_t)(bh * 64 + j) * 64 + d;
            float v = ksum[idx];
            ksump[idx] = run;
            run += v;
        }
        return;
    }
    int e0 = (blockIdx.x * 256 + threadIdx.x) * 4;
    float r0 = 0.f, r1 = 0.f, r2 = 0.f, r3 = 0.f;
    for (int j = 0; j < 64; ++j) {
        size_t idx = (size_t)(bh * 64 + j) * 4096 + e0;
        ushort4 v = *(const ushort4*)&ctxb[idx];
        ushort4 o;
        o.x = (ushort)f2bf(r0); o.y = (ushort)f2bf(r1);
        o.z = (ushort)f2bf(r2); o.w = (ushort)f2bf(r3);
        *(ushort4*)&ctp[idx] = o;
        r0 += bf2f((short)v.x); r1 += bf2f((short)v.y);
        r2 += bf2f((short)v.z); r3 += bf2f((short)v.w);
    }
}

// ---------------- den + attn = q @ ctx * Dinv (q pre-softmaxed in GEMM1) ----------------
__global__ __launch_bounds__(256)
void bucket_attn(const bf16* __restrict__ Qb, const bf16* __restrict__ ctp,
                 const float* __restrict__ ksump, bf16* __restrict__ attn)
{
    __shared__ __align__(16) short q_bf[64 * 64];
    __shared__ __align__(16) short ct_bf[64 * 64];
    __shared__ __align__(16) short at_s[64 * 72];
    __shared__ float dinv_s[64];
    __shared__ float ksum_s[64];
    const int bid = blockIdx.x;
    const int bh = bid >> 6, n = bid & 63;
    const int b = bh >> 4, h = bh & 15;
    const size_t rowbase = (size_t)(b * T_SEQ + n * 64) * 1024 + h * 64;
    const int tid = threadIdx.x;
    const int l = tid & 63, w = tid >> 6;

#pragma unroll
    for (int j = 0; j < 2; ++j) {
        int i = tid + 256 * j;
        int e = i >> 3, dc = i & 7;
        bf16x8s cv = *(const bf16x8s*)&ctp[(size_t)bid * 4096 + e * 64 + dc * 8];
        *(bf16x8s*)&ct_bf[e * 64 + ((dc ^ swz_f(e)) << 3)] = cv;
    }
    if (tid < 64) ksum_s[tid] = ksump[(size_t)bid * 64 + tid];
    __syncthreads();

    // den reduce only (softmax already applied in GEMM1)
#pragma unroll
    for (int i = 0; i < 16; ++i) {
        int s = w * 16 + i;
        float qv = bf2f(*(const short*)&Qb[rowbase + (size_t)s * 1024 + l]);
        float dp = qv * ksum_s[l];
#pragma unroll
        for (int off = 32; off; off >>= 1) dp += __shfl_xor(dp, off);
        if (l == 0) dinv_s[s] = 1.f / fmaxf(dp, 1e-6f);
        q_bf[s * 64 + ((((l >> 3)) ^ swz_f(s)) << 3) + (l & 7)] = f2bf(qv);
    }
    __syncthreads();

    f32x4 acc[4];
#pragma unroll
    for (int i = 0; i < 4; ++i) acc[i] = (f32x4){0.f, 0.f, 0.f, 0.f};
    bf16x8s afr[2], bfr[2][4];
#pragma unroll
    for (int kk = 0; kk < 2; ++kk) {
        int cc = kk * 4 + (l >> 4);
        int r = w * 16 + (l & 15);
        afr[kk] = *(const bf16x8s*)&q_bf[r * 64 + ((cc ^ swz_f(r)) << 3)];
#pragma unroll
        for (int n4 = 0; n4 < 4; ++n4) {
            int e = n4 * 16 + (l & 15);
            bfr[kk][n4] = *(const bf16x8s*)&ct_bf[e * 64 + ((cc ^ swz_f(e)) << 3)];
        }
    }
#pragma unroll
    for (int kk = 0; kk < 2; ++kk)
#pragma unroll
        for (int n4 = 0; n4 < 4; ++n4)
            acc[n4] = MFMA16(afr[kk], bfr[kk][n4], acc[n4]);

#pragma unroll
    for (int n4 = 0; n4 < 4; ++n4) {
        int e = n4 * 16 + (l & 15);
#pragma unroll
        for (int r = 0; r < 4; ++r) {
            int s = w * 16 + ((l >> 4) << 2) + r;
            at_s[s * 72 + e] = f2bf(acc[n4][r] * dinv_s[s]);
        }
    }
    __syncthreads();

#pragma unroll
    for (int j = 0; j < 2; ++j) {
        int i = tid + 256 * j;
        int s = i >> 3, c = i & 7;
        bf16x8s v = *(const bf16x8s*)&at_s[s * 72 + c * 8];
        *(bf16x8s*)&attn[rowbase + (size_t)s * 1024 + c * 8] = v;
    }
}

// ---------------- launch ----------------
extern "C" void kernel_launch(void* const* d_in, const int* in_sizes, int n_in,
                              void* d_out, int out_size, void* d_ws, size_t ws_size,
                              hipStream_t stream)
{
    const float* x    = (const float*)d_in[0];
    const float* Wqkv = (const float*)d_in[1];
    const float* Wout = (const float*)d_in[2];

    char* ws = (char*)d_ws;
    size_t off = 0;
    auto alloc = [&](size_t bytes) { void* p = ws + off; off += (bytes + 255) & ~(size_t)255; return p; };
    bf16*  xb    = (bf16*)alloc((size_t)16384 * 1024 * 2);
    bf16*  wqkvb = (bf16*)alloc((size_t)3072 * 1024 * 2);
    bf16*  woutb = (bf16*)alloc((size_t)1024 * 1024 * 2);
    bf16*  Qb    = (bf16*)alloc((size_t)16384 * 1024 * 2);
    bf16*  ctxb  = (bf16*)alloc((size_t)4096 * 4096 * 2);
    float* ksum  = (float*)alloc((size_t)4096 * 64 * 4);
    bf16*  ctp   = (bf16*)alloc((size_t)4096 * 4096 * 2);
    float* ksump = (float*)alloc((size_t)4096 * 64 * 4);
    bf16*  attnb = xb;                       // xb dead after GEMM1 -> reuse
    float* outf  = (float*)d_out;

    cvt_f32_bf16<<<dim3(16384 * 1024 / 8 / 256), 256, 0, stream>>>(x, xb, 16384 * 1024 / 8);
    cvt_f32_bf16<<<dim3(3072 * 1024 / 8 / 256), 256, 0, stream>>>(Wqkv, wqkvb, 3072 * 1024 / 8);
    cvt_f32_bf16<<<dim3(1024 * 1024 / 8 / 256), 256, 0, stream>>>(Wout, woutb, 1024 * 1024 / 8);

    gemm256<0><<<dim3(12, 64), 512, 0, stream>>>(xb, wqkvb, 1024, 3072, Qb, ctxb, ksum, nullptr);
    cumsum_excl<<<dim3(5, 64), 256, 0, stream>>>(ctxb, ksum, ctp, ksump);
    bucket_attn<<<dim3(4096), 256, 0, stream>>>(Qb, ctp, ksump, attnb);
    gemm256<1><<<dim3(4, 64), 512, 0, stream>>>(attnb, woutb, 1024, 1024, nullptr, nullptr, nullptr, outf);
}

// Round 18
// 227.631 us; speedup vs baseline: 6.9679x; 6.9679x over previous
//
#include <hip/hip_runtime.h>
#include <hip/hip_bf16.h>
#include <math.h>

typedef __hip_bfloat16 bf16;
typedef __attribute__((ext_vector_type(4))) float f32x4;
typedef __attribute__((ext_vector_type(8))) short bf16x8s;

#define T_SEQ 4096
#define MFMA16(a, b, c) __builtin_amdgcn_mfma_f32_16x16x32_bf16(a, b, c, 0, 0, 0)
#define AS1 __attribute__((address_space(1)))
#define AS3 __attribute__((address_space(3)))

static __device__ __forceinline__ float bf2f(short u) {
    return __uint_as_float(((unsigned int)(unsigned short)u) << 16);
}
static __device__ __forceinline__ short f2bf(float f) {
    bf16 h = __float2bfloat16(f);
    union { bf16 b; short s; } c; c.b = h; return c.s;
}
static __device__ __forceinline__ int swz_f(int r) { return (r & 7) ^ (r >> 3); }

// ---------------- f32 -> bf16 conversion (vectorized) ----------------
__global__ void cvt_f32_bf16(const float* __restrict__ src, bf16* __restrict__ dst, int n8) {
    int i = blockIdx.x * 256 + threadIdx.x;
    if (i >= n8) return;
    f32x4 a = ((const f32x4*)src)[(size_t)i * 2];
    f32x4 b = ((const f32x4*)src)[(size_t)i * 2 + 1];
    union { bf16 h[8]; uint4 u; } p;
    p.h[0] = __float2bfloat16(a.x); p.h[1] = __float2bfloat16(a.y);
    p.h[2] = __float2bfloat16(a.z); p.h[3] = __float2bfloat16(a.w);
    p.h[4] = __float2bfloat16(b.x); p.h[5] = __float2bfloat16(b.y);
    p.h[6] = __float2bfloat16(b.z); p.h[7] = __float2bfloat16(b.w);
    ((uint4*)dst)[i] = p.u;
}

// ============ 256x256 tile, BK=64, 8-wave pipelined bf16 GEMM ============
// SESSION BEST (r16: total 227.3 us; gemm<0> 118 us, MfmaUtil 38.9%).
// K-halves h=2t+ks ring over 4 LDS slots (slot = h&3, 8KB per matrix side).
// Distance-3 prefetch: while consuming half h, stage half h+3 into slot
// (h+3)&3 = (h-1)&3 (its reads completed >=2 barriers ago -> WAR safe).
// Per half, 2 phases (m0-3 / m4-7, 16 MFMA each):
//   phA: ds_read bfr[4]+afr[0-3] | stage A-part(h+3) | barrier,MFMA,barrier
//   phB: ds_read afr[4-7]        | stage B-part(h+3) | vmcnt(8) | barrier,MFMA,barrier
// Ledger: 4 loads/half; vmcnt(8)@phB(h) leaves halves h+2,h+3 outstanding ->
// half h+1 complete before its phA(h+1) reads (one barrier later, cross-wave ok).
// Prologue: halves 0-2 + vmcnt(8) + barrier. Tail: vmcnt 8 -> 4 -> 0.
// NOTE (r17): 2-blocks/CU via launch_bounds(512,4) spills acc (needs >=160 regs
// vs 128 cap) -> 10x regression. Keep (512,2).
// MODE 0 (N-grid 12): bx<4 Q block (f32 softmax epilogue); bx>=4 KV block (fused
// exp(K)/V -> ksum + ctx=K^T V, no K/V to HBM). MODE 1: plain f32 out.
template<int MODE>
__global__ __launch_bounds__(512, 2)
void gemm256(const bf16* __restrict__ A, const bf16* __restrict__ Bm,
             int K, int N,
             bf16* __restrict__ out0, bf16* __restrict__ ctxb, float* __restrict__ ksum,
             float* __restrict__ outf)
{
    __shared__ __align__(16) short SMEM[65536];   // A slots: s*8192 ; B slots: 32768 + s*8192
    const int tid  = threadIdx.x;
    const int l    = tid & 63;
    const int wid  = tid >> 6;
    const int wr   = wid >> 2;           // 0..1
    const int wc   = wid & 3;            // 0..3

    // XCD-chunked bijective swizzle (grid % 8 == 0)
    const int nwg  = gridDim.x * gridDim.y;
    const int flat = blockIdx.y * gridDim.x + blockIdx.x;
    const int swzb = (flat & 7) * (nwg >> 3) + (flat >> 3);
    const int bx   = swzb % gridDim.x;
    const int by   = swzb / gridDim.x;
    const int brow = by * 256;
    const int bcol = bx * 256;
    const int nkt  = K >> 6;             // must be even, >= 4

    const bool isKV = (MODE == 0) && (bx >= 4);
    const int  jkv  = bx - 4;
    const int  b0row = isKV ? (1024 + jkv * 128) : bcol;
    const int  b1row = isKV ? (2048 + jkv * 128) : bcol + 128;

    const int chnk = (l >> 4) ^ (((l & 15) >> 1) & 3);
    const short* baseA = &SMEM[(wr * 128 + (l & 15)) * 32 + chnk * 8];
    const short* baseB = &SMEM[32768 + (wc * 64 + (l & 15)) * 32 + chnk * 8];
#define RDA(SLOT, M_) (*(const bf16x8s*)(baseA + (SLOT) * 8192 + (M_) * 512))
#define RDB(SLOT, N_) (*(const bf16x8s*)(baseB + (SLOT) * 8192 + (N_) * 512))

    const int srow = tid >> 2;
    const int scs  = (tid & 3) ^ ((srow >> 1) & 3);
    const bf16* gA0 = A  + (size_t)(brow + srow) * K + scs * 8;
    const bf16* gA1 = A  + (size_t)(brow + 128 + srow) * K + scs * 8;
    const bf16* gB0 = Bm + (size_t)(b0row + srow) * K + scs * 8;
    const bf16* gB1 = Bm + (size_t)(b1row + srow) * K + scs * 8;
#define GLLH(PTR, SLOT, ISB, EXTRA)                                               \
    __builtin_amdgcn_global_load_lds((const AS1 void*)(PTR),                      \
        (AS3 void*)&SMEM[(ISB) * 32768 + (SLOT) * 8192 + (EXTRA) + tid * 8], 16, 0, 0)

#define VM8 asm volatile("s_waitcnt vmcnt(8)" ::: "memory")
#define VM4 asm volatile("s_waitcnt vmcnt(4)" ::: "memory")
#define VM0 asm volatile("s_waitcnt vmcnt(0)" ::: "memory")
#define VMN ((void)0)

    f32x4 acc[8][4];
#pragma unroll
    for (int m = 0; m < 8; ++m)
#pragma unroll
        for (int n = 0; n < 4; ++n) acc[m][n] = (f32x4){0.f, 0.f, 0.f, 0.f};

    // ---- prologue: stage halves 0,1,2 (issue order = ledger order) ----
#pragma unroll
    for (int h = 0; h < 3; ++h) {
        GLLH(gA0 + h * 32, h, 0, 0);  GLLH(gA1 + h * 32, h, 0, 4096);
        GLLH(gB0 + h * 32, h, 1, 0);  GLLH(gB1 + h * 32, h, 1, 4096);
    }
    VM8;                                  // half 0 complete (h1,h2 in flight)
    __builtin_amdgcn_s_barrier();

    // staging pointers -> half 3
    const bf16 *pA0 = gA0 + 96, *pA1 = gA1 + 96, *pB0 = gB0 + 96, *pB1 = gB1 + 96;

#define MFMA_BLOCK(ACCOFF)                                                        \
    __builtin_amdgcn_s_barrier();                                                 \
    __builtin_amdgcn_s_setprio(1);                                                \
    _Pragma("unroll")                                                             \
    for (int m = 0; m < 4; ++m)                                                   \
        _Pragma("unroll")                                                         \
        for (int n = 0; n < 4; ++n)                                               \
            acc[m + (ACCOFF)][n] = MFMA16(afr[m], bfr[n], acc[m + (ACCOFF)][n]);  \
    __builtin_amdgcn_s_setprio(0);                                                \
    __builtin_amdgcn_s_barrier();

#define HALFSTEP(SLOT, PSLOT, PF, VMW)                                            \
    {                                                                             \
        bf16x8s afr[4], bfr[4];                                                   \
        _Pragma("unroll") for (int n = 0; n < 4; ++n) bfr[n] = RDB(SLOT, n);      \
        _Pragma("unroll") for (int m = 0; m < 4; ++m) afr[m] = RDA(SLOT, m);      \
        if (PF) { GLLH(pA0, PSLOT, 0, 0); GLLH(pA1, PSLOT, 0, 4096); }            \
        MFMA_BLOCK(0)                                                             \
        _Pragma("unroll") for (int m = 0; m < 4; ++m) afr[m] = RDA(SLOT, m + 4);  \
        if (PF) { GLLH(pB0, PSLOT, 1, 0); GLLH(pB1, PSLOT, 1, 4096); }            \
        VMW;                                                                      \
        MFMA_BLOCK(4)                                                             \
        pA0 += 32; pA1 += 32; pB0 += 32; pB1 += 32;                               \
    }

    // main: halves 0 .. 2*nkt-5 (stages 3 .. 2*nkt-2)
    for (int g = 0; g < (nkt >> 1) - 1; ++g) {
        HALFSTEP(0, 3, true, VM8)
        HALFSTEP(1, 0, true, VM8)
        HALFSTEP(2, 1, true, VM8)
        HALFSTEP(3, 2, true, VM8)
    }
    // tail: halves 2nkt-4 .. 2nkt-1 (first stages last half 2nkt-1)
    HALFSTEP(0, 3, true,  VM8)
    HALFSTEP(1, 0, false, VM4)
    HALFSTEP(2, 1, false, VM0)
    HALFSTEP(3, 2, false, VMN)

    if (MODE == 1) {
#pragma unroll
        for (int m = 0; m < 8; ++m) {
            int row = brow + wr * 128 + m * 16 + ((l >> 4) << 2);
#pragma unroll
            for (int n = 0; n < 4; ++n) {
                int col = bcol + wc * 64 + n * 16 + (l & 15);
#pragma unroll
                for (int r = 0; r < 4; ++r)
                    outf[(size_t)(row + r) * N + col] = acc[m][n][r];
            }
        }
    } else if (!isKV) {
        // ---- Q epilogue: f32 row-softmax over the 64-wide head (this wave's wc) ----
#pragma unroll
        for (int m = 0; m < 8; ++m) {
            int row = brow + wr * 128 + m * 16 + ((l >> 4) << 2);
#pragma unroll
            for (int r = 0; r < 4; ++r) {
                float v0 = acc[m][0][r], v1 = acc[m][1][r], v2 = acc[m][2][r], v3 = acc[m][3][r];
                float mx = fmaxf(fmaxf(v0, v1), fmaxf(v2, v3));
#pragma unroll
                for (int off = 8; off; off >>= 1) mx = fmaxf(mx, __shfl_xor(mx, off));
                float e0 = __expf(v0 - mx), e1 = __expf(v1 - mx);
                float e2 = __expf(v2 - mx), e3 = __expf(v3 - mx);
                float sm = e0 + e1 + e2 + e3;
#pragma unroll
                for (int off = 8; off; off >>= 1) sm += __shfl_xor(sm, off);
                float inv = 0.125f / sm;
                size_t rr = (size_t)(row + r);
                int cb = bcol + wc * 64 + (l & 15);
                out0[rr * 1024 + cb]      = __float2bfloat16(e0 * inv);
                out0[rr * 1024 + cb + 16] = __float2bfloat16(e1 * inv);
                out0[rr * 1024 + cb + 32] = __float2bfloat16(e2 * inv);
                out0[rr * 1024 + cb + 48] = __float2bfloat16(e3 * inv);
            }
        }
    } else {
        // ---- KV epilogue: packed b64 scatter + register ksum ----
        const int hl = wc & 1;                       // head_local (K: wc 0,1; V: wc 2,3)
        short* side = (short*)SMEM + ((wc >= 2) ? 32768 : 0);
        float ks[2][4];
#pragma unroll
        for (int u = 0; u < 2; ++u)
#pragma unroll
            for (int n = 0; n < 4; ++n) ks[u][n] = 0.f;
#pragma unroll
        for (int m = 0; m < 8; ++m) {
            const int ubase = wr * 16384 + (m >> 2) * 8192 + hl * 4096;  // unit*4096
            const int s0 = (m & 3) * 16 + ((l >> 4) << 2);
            const int sc = s0 >> 3, slo = s0 & 7;
#pragma unroll
            for (int n = 0; n < 4; ++n) {
                int d = n * 16 + (l & 15);
                union { short h4[4]; uint2 u2; } pk;
                if (wc < 2) {
                    float e0 = __expf(acc[m][n][0]), e1 = __expf(acc[m][n][1]);
                    float e2 = __expf(acc[m][n][2]), e3 = __expf(acc[m][n][3]);
                    ks[m >> 2][n] += (e0 + e1) + (e2 + e3);
                    pk.h4[0] = f2bf(e0); pk.h4[1] = f2bf(e1);
                    pk.h4[2] = f2bf(e2); pk.h4[3] = f2bf(e3);
                } else {
                    pk.h4[0] = f2bf(acc[m][n][0]); pk.h4[1] = f2bf(acc[m][n][1]);
                    pk.h4[2] = f2bf(acc[m][n][2]); pk.h4[3] = f2bf(acc[m][n][3]);
                }
                *(uint2*)&side[ubase + d * 64 + ((sc ^ swz_f(d)) << 3) + slo] = pk.u2;
            }
        }
        if (wc < 2) {   // finish ksum: lanes l, l^16, l^32 share d
#pragma unroll
            for (int u = 0; u < 2; ++u)
#pragma unroll
                for (int n = 0; n < 4; ++n) {
                    float s = ks[u][n];
                    s += __shfl_xor(s, 16);
                    s += __shfl_xor(s, 32);
                    if ((l >> 4) == 0) {
                        int unit = wr * 4 + u * 2 + hl;
                        int gr0 = brow + (unit >> 1) * 64;
                        size_t bidu = (size_t)(((gr0 >> 12) * 16) + jkv * 2 + (unit & 1)) * 64
                                      + ((gr0 & 4095) >> 6);
                        ksum[bidu * 64 + n * 16 + (l & 15)] = s;
                    }
                }
        }
        __syncthreads();

        // step 2: wave wid owns unit wid; ctx = K^T V (32 MFMA)
        const int gr0 = brow + (wid >> 1) * 64;
        const size_t bid = (size_t)(((gr0 >> 12) * 16) + jkv * 2 + (wid & 1)) * 64
                           + ((gr0 & 4095) >> 6);
        const short* k_u = (const short*)SMEM + wid * 4096;
        const short* v_u = (const short*)SMEM + 32768 + wid * 4096;

        f32x4 a16[4][4];
#pragma unroll
        for (int m = 0; m < 4; ++m)
#pragma unroll
            for (int n = 0; n < 4; ++n) a16[m][n] = (f32x4){0.f, 0.f, 0.f, 0.f};
#pragma unroll
        for (int kk = 0; kk < 2; ++kk) {
            const int cc = kk * 4 + (l >> 4);
            bf16x8s af[4], bf[4];
#pragma unroll
            for (int m = 0; m < 4; ++m) {
                int rA = m * 16 + (l & 15);
                af[m] = *(const bf16x8s*)&k_u[rA * 64 + ((cc ^ swz_f(rA)) << 3)];
                bf[m] = *(const bf16x8s*)&v_u[rA * 64 + ((cc ^ swz_f(rA)) << 3)];
            }
#pragma unroll
            for (int m = 0; m < 4; ++m)
#pragma unroll
                for (int n = 0; n < 4; ++n)
                    a16[m][n] = MFMA16(af[m], bf[n], a16[m][n]);
        }
        bf16* rec = ctxb + bid * 4096;
#pragma unroll
        for (int m = 0; m < 4; ++m) {
            int d0 = m * 16 + ((l >> 4) << 2);
#pragma unroll
            for (int n = 0; n < 4; ++n) {
                int e = n * 16 + (l & 15);
                ushort4 o;
                o.x = (ushort)f2bf(a16[m][n][0]); o.y = (ushort)f2bf(a16[m][n][1]);
                o.z = (ushort)f2bf(a16[m][n][2]); o.w = (ushort)f2bf(a16[m][n][3]);
                *(ushort4*)&rec[e * 64 + d0] = o;
            }
        }
    }
#undef RDA
#undef RDB
#undef GLLH
#undef MFMA_BLOCK
#undef HALFSTEP
#undef VM8
#undef VM4
#undef VM0
#undef VMN
}

// ---------------- exclusive cumsum over buckets ----------------
// grid (5, 64): x<4 -> ctx chains (bf16 in, f32 accum, bf16 out); x==4 -> ksum (f32)
__global__ void cumsum_excl(const bf16* __restrict__ ctxb, const float* __restrict__ ksum,
                            bf16* __restrict__ ctp, float* __restrict__ ksump)
{
    const int bh = blockIdx.y;
    if (blockIdx.x == 4) {
        int d = threadIdx.x;
        if (d >= 64) return;
        float run = 0.f;
        for (int j = 0; j < 64; ++j) {
            size_t idx = (size_t)(bh * 64 + j) * 64 + d;
            float v = ksum[idx];
            ksump[idx] = run;
            run += v;
        }
        return;
    }
    int e0 = (blockIdx.x * 256 + threadIdx.x) * 4;
    float r0 = 0.f, r1 = 0.f, r2 = 0.f, r3 = 0.f;
    for (int j = 0; j < 64; ++j) {
        size_t idx = (size_t)(bh * 64 + j) * 4096 + e0;
        ushort4 v = *(const ushort4*)&ctxb[idx];
        ushort4 o;
        o.x = (ushort)f2bf(r0); o.y = (ushort)f2bf(r1);
        o.z = (ushort)f2bf(r2); o.w = (ushort)f2bf(r3);
        *(ushort4*)&ctp[idx] = o;
        r0 += bf2f((short)v.x); r1 += bf2f((short)v.y);
        r2 += bf2f((short)v.z); r3 += bf2f((short)v.w);
    }
}

// ---------------- den + attn = q @ ctx * Dinv (q pre-softmaxed in GEMM1) ----------------
__global__ __launch_bounds__(256)
void bucket_attn(const bf16* __restrict__ Qb, const bf16* __restrict__ ctp,
                 const float* __restrict__ ksump, bf16* __restrict__ attn)
{
    __shared__ __align__(16) short q_bf[64 * 64];
    __shared__ __align__(16) short ct_bf[64 * 64];
    __shared__ __align__(16) short at_s[64 * 72];
    __shared__ float dinv_s[64];
    __shared__ float ksum_s[64];
    const int bid = blockIdx.x;
    const int bh = bid >> 6, n = bid & 63;
    const int b = bh >> 4, h = bh & 15;
    const size_t rowbase = (size_t)(b * T_SEQ + n * 64) * 1024 + h * 64;
    const int tid = threadIdx.x;
    const int l = tid & 63, w = tid >> 6;

#pragma unroll
    for (int j = 0; j < 2; ++j) {
        int i = tid + 256 * j;
        int e = i >> 3, dc = i & 7;
        bf16x8s cv = *(const bf16x8s*)&ctp[(size_t)bid * 4096 + e * 64 + dc * 8];
        *(bf16x8s*)&ct_bf[e * 64 + ((dc ^ swz_f(e)) << 3)] = cv;
    }
    if (tid < 64) ksum_s[tid] = ksump[(size_t)bid * 64 + tid];
    __syncthreads();

    // den reduce only (softmax already applied in GEMM1)
#pragma unroll
    for (int i = 0; i < 16; ++i) {
        int s = w * 16 + i;
        float qv = bf2f(*(const short*)&Qb[rowbase + (size_t)s * 1024 + l]);
        float dp = qv * ksum_s[l];
#pragma unroll
        for (int off = 32; off; off >>= 1) dp += __shfl_xor(dp, off);
        if (l == 0) dinv_s[s] = 1.f / fmaxf(dp, 1e-6f);
        q_bf[s * 64 + ((((l >> 3)) ^ swz_f(s)) << 3) + (l & 7)] = f2bf(qv);
    }
    __syncthreads();

    f32x4 acc[4];
#pragma unroll
    for (int i = 0; i < 4; ++i) acc[i] = (f32x4){0.f, 0.f, 0.f, 0.f};
    bf16x8s afr[2], bfr[2][4];
#pragma unroll
    for (int kk = 0; kk < 2; ++kk) {
        int cc = kk * 4 + (l >> 4);
        int r = w * 16 + (l & 15);
        afr[kk] = *(const bf16x8s*)&q_bf[r * 64 + ((cc ^ swz_f(r)) << 3)];
#pragma unroll
        for (int n4 = 0; n4 < 4; ++n4) {
            int e = n4 * 16 + (l & 15);
            bfr[kk][n4] = *(const bf16x8s*)&ct_bf[e * 64 + ((cc ^ swz_f(e)) << 3)];
        }
    }
#pragma unroll
    for (int kk = 0; kk < 2; ++kk)
#pragma unroll
        for (int n4 = 0; n4 < 4; ++n4)
            acc[n4] = MFMA16(afr[kk], bfr[kk][n4], acc[n4]);

#pragma unroll
    for (int n4 = 0; n4 < 4; ++n4) {
        int e = n4 * 16 + (l & 15);
#pragma unroll
        for (int r = 0; r < 4; ++r) {
            int s = w * 16 + ((l >> 4) << 2) + r;
            at_s[s * 72 + e] = f2bf(acc[n4][r] * dinv_s[s]);
        }
    }
    __syncthreads();

#pragma unroll
    for (int j = 0; j < 2; ++j) {
        int i = tid + 256 * j;
        int s = i >> 3, c = i & 7;
        bf16x8s v = *(const bf16x8s*)&at_s[s * 72 + c * 8];
        *(bf16x8s*)&attn[rowbase + (size_t)s * 1024 + c * 8] = v;
    }
}

// ---------------- launch ----------------
extern "C" void kernel_launch(void* const* d_in, const int* in_sizes, int n_in,
                              void* d_out, int out_size, void* d_ws, size_t ws_size,
                              hipStream_t stream)
{
    const float* x    = (const float*)d_in[0];
    const float* Wqkv = (const float*)d_in[1];
    const float* Wout = (const float*)d_in[2];

    char* ws = (char*)d_ws;
    size_t off = 0;
    auto alloc = [&](size_t bytes) { void* p = ws + off; off += (bytes + 255) & ~(size_t)255; return p; };
    bf16*  xb    = (bf16*)alloc((size_t)16384 * 1024 * 2);
    bf16*  wqkvb = (bf16*)alloc((size_t)3072 * 1024 * 2);
    bf16*  woutb = (bf16*)alloc((size_t)1024 * 1024 * 2);
    bf16*  Qb    = (bf16*)alloc((size_t)16384 * 1024 * 2);
    bf16*  ctxb  = (bf16*)alloc((size_t)4096 * 4096 * 2);
    float* ksum  = (float*)alloc((size_t)4096 * 64 * 4);
    bf16*  ctp   = (bf16*)alloc((size_t)4096 * 4096 * 2);
    float* ksump = (float*)alloc((size_t)4096 * 64 * 4);
    bf16*  attnb = xb;                       // xb dead after GEMM1 -> reuse
    float* outf  = (float*)d_out;

    cvt_f32_bf16<<<dim3(16384 * 1024 / 8 / 256), 256, 0, stream>>>(x, xb, 16384 * 1024 / 8);
    cvt_f32_bf16<<<dim3(3072 * 1024 / 8 / 256), 256, 0, stream>>>(Wqkv, wqkvb, 3072 * 1024 / 8);
    cvt_f32_bf16<<<dim3(1024 * 1024 / 8 / 256), 256, 0, stream>>>(Wout, woutb, 1024 * 1024 / 8);

    gemm256<0><<<dim3(12, 64), 512, 0, stream>>>(xb, wqkvb, 1024, 3072, Qb, ctxb, ksum, nullptr);
    cumsum_excl<<<dim3(5, 64), 256, 0, stream>>>(ctxb, ksum, ctp, ksump);
    bucket_attn<<<dim3(4096), 256, 0, stream>>>(Qb, ctp, ksump, attnb);
    gemm256<1><<<dim3(4, 64), 512, 0, stream>>>(attnb, woutb, 1024, 1024, nullptr, nullptr, nullptr, outf);
}